// Round 12
// baseline (1938.247 us; speedup 1.0000x reference)
//
#include <hip/hip_runtime.h>
#include <math.h>

#define NS 8192
#define DS 64
#define HD 4096
#define C2L 2.8853900817779268f   // 2*log2(e)
#define CH 4                      // steps per chunk (16 KB parts -> high occupancy)
#define NCH (DS / CH)

typedef float v2f __attribute__((ext_vector_type(2)));

__device__ __forceinline__ v2f pk_add(v2f a, v2f b) {
    v2f d; asm("v_pk_add_f32 %0, %1, %2" : "=v"(d) : "v"(a), "v"(b)); return d;
}
__device__ __forceinline__ v2f pk_mul(v2f a, v2f b) {
    v2f d; asm("v_pk_mul_f32 %0, %1, %2" : "=v"(d) : "v"(a), "v"(b)); return d;
}
__device__ __forceinline__ v2f pk_fma(v2f a, v2f b, v2f c) {
    v2f d; asm("v_pk_fma_f32 %0, %1, %2, %3" : "=v"(d) : "v"(a), "v"(b), "v"(c)); return d;
}

__device__ __forceinline__ float fast_tanh(float x) {
    float t = __builtin_amdgcn_exp2f(x * C2L);
    float r = __builtin_amdgcn_rcpf(t + 1.0f);
    return __builtin_fmaf(-2.0f, r, 1.0f);
}

template <int PATT>
__device__ __forceinline__ v2f swz_xor(v2f v) {
    v2f d;
    d.x = __int_as_float(__builtin_amdgcn_ds_swizzle(__float_as_int(v.x), PATT));
    d.y = __int_as_float(__builtin_amdgcn_ds_swizzle(__float_as_int(v.y), PATT));
    return d;
}

// ---- setup: Et[0][d][h]=e^{+2W1}, Et[1][d][h]=e^{-2W1}; C01 = colsum(W2)+b2 ----
__global__ __launch_bounds__(256) void qnade_prep_E(
    const float* __restrict__ W1, float* __restrict__ Et)
{
    int i = blockIdx.x * 256 + threadIdx.x;
    float w = W1[i] * C2L;
    Et[i]           = __builtin_amdgcn_exp2f(w);
    Et[DS * HD + i] = __builtin_amdgcn_exp2f(-w);
}

__global__ __launch_bounds__(256) void qnade_prep_S(
    const float* __restrict__ W2, const float* __restrict__ b2, float* __restrict__ C01)
{
    __shared__ float p0[4], p1[4];
    int tid = threadIdx.x;
    float s0 = 0.0f, s1 = 0.0f;
    for (int h = tid; h < HD; h += 256) {
        float2 w = ((const float2*)W2)[h];
        s0 += w.x; s1 += w.y;
    }
    #pragma unroll
    for (int m = 1; m < 64; m <<= 1) {
        s0 += __shfl_xor(s0, m, 64);
        s1 += __shfl_xor(s1, m, 64);
    }
    if ((tid & 63) == 0) { p0[tid >> 6] = s0; p1[tid >> 6] = s1; }
    __syncthreads();
    if (tid == 0) {
        C01[0] = p0[0] + p0[1] + p0[2] + p0[3] + b2[0];
        C01[1] = p1[0] + p1[1] + p1[2] + p1[3] + b2[1];
    }
}

// token-paste helpers (complete paste BEFORE member access)
#define TV(S, N) t##S##N
#define EV(S, N) e##S##N
#define FV(S, N) f##S##N

// Montgomery batch inversion + fused recovery/dot; one ds_write_b64 at end.
#define CHAIN(S, MIDX, SLOT) do {                                             \
    v2f q1 = pk_add(TV(S,0), one);                                            \
    v2f q2 = pk_fma(q1, TV(S,1), q1);                                         \
    v2f q3 = pk_fma(q2, TV(S,2), q2);                                         \
    v2f q4 = pk_fma(q3, TV(S,3), q3);                                         \
    v2f q5 = pk_fma(q4, TV(S,4), q4);                                         \
    v2f q6 = pk_fma(q5, TV(S,5), q5);                                         \
    v2f q7 = pk_fma(q6, TV(S,6), q6);                                         \
    v2f q8 = pk_fma(q7, TV(S,7), q7);                                         \
    float P = q8.x * q8.y;                                                    \
    float R = __builtin_amdgcn_rcpf(P);                                       \
    v2f RR = (v2f){R * q8.y, R * q8.x};                                       \
    v2f r7 = pk_mul(RR, q7);                                                  \
    v2f A0 = pk_mul(r7, w20[7]);                                              \
    v2f A1 = pk_mul(r7, w21[7]);                                              \
    RR = pk_fma(RR, TV(S,7), RR);                                             \
    v2f r6 = pk_mul(RR, q6); A0 = pk_fma(r6, w20[6], A0); A1 = pk_fma(r6, w21[6], A1); RR = pk_fma(RR, TV(S,6), RR); \
    v2f r5 = pk_mul(RR, q5); A0 = pk_fma(r5, w20[5], A0); A1 = pk_fma(r5, w21[5], A1); RR = pk_fma(RR, TV(S,5), RR); \
    v2f r4 = pk_mul(RR, q4); A0 = pk_fma(r4, w20[4], A0); A1 = pk_fma(r4, w21[4], A1); RR = pk_fma(RR, TV(S,4), RR); \
    v2f r3 = pk_mul(RR, q3); A0 = pk_fma(r3, w20[3], A0); A1 = pk_fma(r3, w21[3], A1); RR = pk_fma(RR, TV(S,3), RR); \
    v2f r2 = pk_mul(RR, q2); A0 = pk_fma(r2, w20[2], A0); A1 = pk_fma(r2, w21[2], A1); RR = pk_fma(RR, TV(S,2), RR); \
    v2f r1 = pk_mul(RR, q1); A0 = pk_fma(r1, w20[1], A0); A1 = pk_fma(r1, w21[1], A1); RR = pk_fma(RR, TV(S,1), RR); \
    A0 = pk_fma(RR, w20[0], A0); A1 = pk_fma(RR, w21[0], A1);                 \
    parts[MIDX][SLOT][tid] = make_float2(A0.x + A0.y, A1.x + A1.y);           \
} while (0)

#define TUPD_E(S) do {                                                        \
    TV(S,0) = pk_mul(TV(S,0), (v2f){EV(S,0).x, EV(S,0).y});                   \
    TV(S,1) = pk_mul(TV(S,1), (v2f){EV(S,0).z, EV(S,0).w});                   \
    TV(S,2) = pk_mul(TV(S,2), (v2f){EV(S,1).x, EV(S,1).y});                   \
    TV(S,3) = pk_mul(TV(S,3), (v2f){EV(S,1).z, EV(S,1).w});                   \
    TV(S,4) = pk_mul(TV(S,4), (v2f){EV(S,2).x, EV(S,2).y});                   \
    TV(S,5) = pk_mul(TV(S,5), (v2f){EV(S,2).z, EV(S,2).w});                   \
    TV(S,6) = pk_mul(TV(S,6), (v2f){EV(S,3).x, EV(S,3).y});                   \
    TV(S,7) = pk_mul(TV(S,7), (v2f){EV(S,3).z, EV(S,3).w});                   \
} while (0)

#define TUPD_F(S) do {                                                        \
    TV(S,0) = pk_mul(TV(S,0), (v2f){FV(S,0).x, FV(S,0).y});                   \
    TV(S,1) = pk_mul(TV(S,1), (v2f){FV(S,0).z, FV(S,0).w});                   \
    TV(S,2) = pk_mul(TV(S,2), (v2f){FV(S,1).x, FV(S,1).y});                   \
    TV(S,3) = pk_mul(TV(S,3), (v2f){FV(S,1).z, FV(S,1).w});                   \
    TV(S,4) = pk_mul(TV(S,4), (v2f){FV(S,2).x, FV(S,2).y});                   \
    TV(S,5) = pk_mul(TV(S,5), (v2f){FV(S,2).z, FV(S,2).w});                   \
    TV(S,6) = pk_mul(TV(S,6), (v2f){FV(S,3).x, FV(S,3).y});                   \
    TV(S,7) = pk_mul(TV(S,7), (v2f){FV(S,3).z, FV(S,3).w});                   \
} while (0)

#define LOAD_E(S) do {                                                        \
    unsigned off_ = (((msk##S >> nd) & 1ull) ? 0u : (unsigned)(DS * HD)) + nd * (unsigned)HD; \
    const float4* ep_ = (const float4*)(Et + off_) + tq;                      \
    EV(S,0) = ep_[0]; EV(S,1) = ep_[64]; EV(S,2) = ep_[128]; EV(S,3) = ep_[192]; \
} while (0)

#define LOAD_F(S) do {                                                        \
    unsigned off_ = (((msk##S >> nd) & 1ull) ? 0u : (unsigned)(DS * HD)) + nd * (unsigned)HD; \
    const float4* ep_ = (const float4*)(Et + off_) + tq;                      \
    FV(S,0) = ep_[0]; FV(S,1) = ep_[64]; FV(S,2) = ep_[128]; FV(S,3) = ep_[192]; \
} while (0)

// ---- main: one block = 2 samples; each wave owns a 1024-elem quarter.
// E registers double-buffered (ping-pong, unroll-2). CH=4 keeps LDS ~17 KB so
// occupancy is VGPR-limited (~6 waves/SIMD), doubling TLP vs CH=8.
__global__ __launch_bounds__(256, 4) void qnade_main(
    const float* __restrict__ x, const float* __restrict__ b1,
    const float* __restrict__ W2, const float* __restrict__ Et,
    const float* __restrict__ C01, float* __restrict__ out)
{
    __shared__ float2 parts[2][CH][256];   // 16 KB
    __shared__ float2 fin[2][DS];          // 1 KB

    const int tid  = threadIdx.x;
    const int lane = tid & 63;
    const int wv   = tid >> 6;
    const int n0   = blockIdx.x * 2;
    const int hbase = wv * 1024 + lane * 4;   // + q*256
    const int tq    = wv * 256 + lane;        // float4 index of hbase

    // W2 columns as (even,odd)-element pairs — shared by both samples
    v2f w20[8], w21[8];
    #pragma unroll
    for (int q = 0; q < 4; ++q) {
        const float4* p = (const float4*)(W2 + 2 * (hbase + q * 256));
        float4 A = p[0], B = p[1];
        w20[2*q]   = (v2f){A.x, A.z};  w21[2*q]   = (v2f){A.y, A.w};
        w20[2*q+1] = (v2f){B.x, B.z};  w21[2*q+1] = (v2f){B.y, B.w};
    }

    // t0 = e^{2*b1}, identical start for both samples
    v2f tA0, tA1, tA2, tA3, tA4, tA5, tA6, tA7;
    {
        float4 b0 = *(const float4*)(b1 + hbase);
        float4 b1q = *(const float4*)(b1 + hbase + 256);
        float4 b2q = *(const float4*)(b1 + hbase + 512);
        float4 b3q = *(const float4*)(b1 + hbase + 768);
        tA0 = (v2f){__builtin_amdgcn_exp2f(b0.x * C2L), __builtin_amdgcn_exp2f(b0.y * C2L)};
        tA1 = (v2f){__builtin_amdgcn_exp2f(b0.z * C2L), __builtin_amdgcn_exp2f(b0.w * C2L)};
        tA2 = (v2f){__builtin_amdgcn_exp2f(b1q.x * C2L), __builtin_amdgcn_exp2f(b1q.y * C2L)};
        tA3 = (v2f){__builtin_amdgcn_exp2f(b1q.z * C2L), __builtin_amdgcn_exp2f(b1q.w * C2L)};
        tA4 = (v2f){__builtin_amdgcn_exp2f(b2q.x * C2L), __builtin_amdgcn_exp2f(b2q.y * C2L)};
        tA5 = (v2f){__builtin_amdgcn_exp2f(b2q.z * C2L), __builtin_amdgcn_exp2f(b2q.w * C2L)};
        tA6 = (v2f){__builtin_amdgcn_exp2f(b3q.x * C2L), __builtin_amdgcn_exp2f(b3q.y * C2L)};
        tA7 = (v2f){__builtin_amdgcn_exp2f(b3q.z * C2L), __builtin_amdgcn_exp2f(b3q.w * C2L)};
    }
    v2f tB0=tA0, tB1=tA1, tB2=tA2, tB3=tA3, tB4=tA4, tB5=tA5, tB6=tA6, tB7=tA7;

    const unsigned long long mskA = __ballot(x[n0 * DS + lane] > 0.0f);
    const unsigned long long mskB = __ballot(x[(n0 + 1) * DS + lane] > 0.0f);
    const v2f one = (v2f){1.0f, 1.0f};

    float4 eA0, eA1, eA2, eA3, eB0, eB1, eB2, eB3;   // buffer E (even steps)
    float4 fA0, fA1, fA2, fA3, fB0, fB1, fB2, fB3;   // buffer F (odd steps)

    unsigned nd = 0;
    LOAD_E(A); LOAD_E(B);      // step 0
    nd = 1;
    LOAD_F(A); LOAD_F(B);      // step 1

    int d = 0;
    for (int cc = 0; cc < NCH; ++cc) {
        for (int s8 = 0; s8 < CH; s8 += 2) {
            // even step d: consume E, then reload E for d+2
            CHAIN(A, 0, s8);
            CHAIN(B, 1, s8);
            TUPD_E(A); TUPD_E(B);
            nd = (unsigned)(d + 2) & (DS - 1);
            LOAD_E(A); LOAD_E(B);
            ++d;
            // odd step d: consume F, then reload F for d+2
            CHAIN(A, 0, s8 + 1);
            CHAIN(B, 1, s8 + 1);
            TUPD_F(A); TUPD_F(B);
            nd = (unsigned)(d + 2) & (DS - 1);
            LOAD_F(A); LOAD_F(B);
            ++d;
        }

        __syncthreads();
        // chunk reduce: 8 (sample,step) units x 256 partials; 32 threads/unit
        {
            const int j  = tid & 31;
            const int u  = tid >> 5;          // 0..7
            const int m  = u & 1;
            const int sr = u >> 1;            // 0..3
            v2f s = (v2f){0.0f, 0.0f};
            #pragma unroll
            for (int i = 0; i < 8; ++i) {
                float2 v = parts[m][sr][j + 32 * i];
                s = pk_add(s, (v2f){v.x, v.y});
            }
            s = pk_add(s, swz_xor<0x041F>(s));   // xor 1
            s = pk_add(s, swz_xor<0x081F>(s));   // xor 2
            s = pk_add(s, swz_xor<0x101F>(s));   // xor 4
            s = pk_add(s, swz_xor<0x201F>(s));   // xor 8
            s = pk_add(s, swz_xor<0x401F>(s));   // xor 16
            if (j == 0) fin[m][cc * CH + sr] = make_float2(s.x, s.y);
        }
        __syncthreads();
    }

    // deferred epilogue: wave 0 -> sample A, wave 1 -> sample B; lane = step
    if (wv < 2) {
        const unsigned long long mm = wv ? mskB : mskA;
        float2 sv = fin[wv][lane];
        float dot0 = __builtin_fmaf(-2.0f, sv.x, C01[0]);
        float dot1 = __builtin_fmaf(-2.0f, sv.y, C01[1]);
        float o0 = fast_tanh(dot0);
        float o1 = fast_tanh(dot1);
        float nrm = sqrtf(__builtin_fmaf(o0, o0, o1 * o1));
        nrm = fmaxf(nrm, 1e-12f);
        float sel = ((mm >> lane) & 1ull) ? o0 : o1;
        float v = sel * __builtin_amdgcn_rcpf(nrm);
        v *= __shfl_xor(v, 1, 64);
        v *= __shfl_xor(v, 2, 64);
        v *= __shfl_xor(v, 4, 64);
        v *= __shfl_xor(v, 8, 64);
        v *= __shfl_xor(v, 16, 64);
        v *= __shfl_xor(v, 32, 64);
        if (lane == 0) out[n0 + wv] = v;
    }
}

// ---- fallback if ws too small ----
__global__ __launch_bounds__(256) void qnade_fallback(
    const float* __restrict__ x, const float* __restrict__ W1,
    const float* __restrict__ b1, const float* __restrict__ W2,
    const float* __restrict__ b2, float* __restrict__ out)
{
    __shared__ __align__(16) float w20s[HD];
    __shared__ __align__(16) float w21s[HD];
    const int tid = threadIdx.x;
    for (int i = tid; i < HD; i += 256) {
        float2 w = ((const float2*)W2)[i];
        w20s[i] = w.x;
        w21s[i] = w.y;
    }
    const int lane = tid & 63;
    const int wv   = tid >> 6;
    const int n    = (blockIdx.x << 2) + wv;
    const float b20 = b2[0];
    const float b21 = b2[1];
    const float xv = x[n * DS + lane];
    float4 a[16];
    const float4* b1v = (const float4*)b1;
    #pragma unroll
    for (int q = 0; q < 16; ++q) a[q] = b1v[q * 64 + lane];
    __syncthreads();
    const float4* w20v = (const float4*)w20s;
    const float4* w21v = (const float4*)w21s;
    float wav = 1.0f;
    for (int d = 0; d < DS; ++d) {
        const float xd = __shfl(xv, d, 64);
        const float4* w1v = (const float4*)(W1 + d * HD);
        float dot0 = 0.0f, dot1 = 0.0f;
        #pragma unroll
        for (int q = 0; q < 16; ++q) {
            float4 w1 = w1v[q * 64 + lane];
            float4 av = a[q];
            float h0 = fast_tanh(av.x);
            float h1 = fast_tanh(av.y);
            float h2 = fast_tanh(av.z);
            float h3 = fast_tanh(av.w);
            float4 c0 = w20v[q * 64 + lane];
            float4 c1 = w21v[q * 64 + lane];
            dot0 = fmaf(h0, c0.x, dot0); dot0 = fmaf(h1, c0.y, dot0);
            dot0 = fmaf(h2, c0.z, dot0); dot0 = fmaf(h3, c0.w, dot0);
            dot1 = fmaf(h0, c1.x, dot1); dot1 = fmaf(h1, c1.y, dot1);
            dot1 = fmaf(h2, c1.z, dot1); dot1 = fmaf(h3, c1.w, dot1);
            av.x = fmaf(xd, w1.x, av.x); av.y = fmaf(xd, w1.y, av.y);
            av.z = fmaf(xd, w1.z, av.z); av.w = fmaf(xd, w1.w, av.w);
            a[q] = av;
        }
        #pragma unroll
        for (int m = 1; m < 64; m <<= 1) {
            dot0 += __shfl_xor(dot0, m, 64);
            dot1 += __shfl_xor(dot1, m, 64);
        }
        float o0 = fast_tanh(dot0 + b20);
        float o1 = fast_tanh(dot1 + b21);
        float nrm = sqrtf(fmaf(o0, o0, o1 * o1));
        nrm = fmaxf(nrm, 1e-12f);
        float sel = (xd > 0.0f) ? o0 : o1;
        wav *= sel / nrm;
    }
    out[n] = wav;
}

extern "C" void kernel_launch(void* const* d_in, const int* in_sizes, int n_in,
                              void* d_out, int out_size, void* d_ws, size_t ws_size,
                              hipStream_t stream) {
    const float* x  = (const float*)d_in[0];
    const float* W1 = (const float*)d_in[1];
    const float* b1 = (const float*)d_in[2];
    const float* W2 = (const float*)d_in[3];
    const float* b2 = (const float*)d_in[4];
    float* out = (float*)d_out;

    const size_t need = (size_t)(2 * DS * HD + 2) * sizeof(float);
    if (ws_size >= need) {
        float* Et  = (float*)d_ws;           // [2][DS][HD]
        float* C01 = Et + 2 * DS * HD;
        hipLaunchKernelGGL(qnade_prep_E, dim3(DS * HD / 256), dim3(256), 0, stream, W1, Et);
        hipLaunchKernelGGL(qnade_prep_S, dim3(1), dim3(256), 0, stream, W2, b2, C01);
        hipLaunchKernelGGL(qnade_main, dim3(NS / 2), dim3(256), 0, stream, x, b1, W2, Et, C01, out);
    } else {
        hipLaunchKernelGGL(qnade_fallback, dim3(NS / 4), dim3(256), 0, stream, x, W1, b1, W2, b2, out);
    }
}

// Round 13
// 412.781 us; speedup vs baseline: 4.6956x; 4.6956x over previous
//
#include <hip/hip_runtime.h>
#include <math.h>

#define NS 8192
#define DS 64
#define HD 4096
#define C2L 2.8853900817779268f   // 2*log2(e)
#define CH 4                      // steps per chunk (16 KB parts -> high occupancy)
#define NCH (DS / CH)

typedef float v2f __attribute__((ext_vector_type(2)));

__device__ __forceinline__ v2f pk_add(v2f a, v2f b) {
    v2f d; asm("v_pk_add_f32 %0, %1, %2" : "=v"(d) : "v"(a), "v"(b)); return d;
}
__device__ __forceinline__ v2f pk_mul(v2f a, v2f b) {
    v2f d; asm("v_pk_mul_f32 %0, %1, %2" : "=v"(d) : "v"(a), "v"(b)); return d;
}
__device__ __forceinline__ v2f pk_fma(v2f a, v2f b, v2f c) {
    v2f d; asm("v_pk_fma_f32 %0, %1, %2, %3" : "=v"(d) : "v"(a), "v"(b), "v"(c)); return d;
}

__device__ __forceinline__ float fast_tanh(float x) {
    float t = __builtin_amdgcn_exp2f(x * C2L);
    float r = __builtin_amdgcn_rcpf(t + 1.0f);
    return __builtin_fmaf(-2.0f, r, 1.0f);
}

template <int PATT>
__device__ __forceinline__ v2f swz_xor(v2f v) {
    v2f d;
    d.x = __int_as_float(__builtin_amdgcn_ds_swizzle(__float_as_int(v.x), PATT));
    d.y = __int_as_float(__builtin_amdgcn_ds_swizzle(__float_as_int(v.y), PATT));
    return d;
}

// ---- setup: Et[0][d][h]=e^{+2W1}, Et[1][d][h]=e^{-2W1}; C01 = colsum(W2)+b2 ----
__global__ __launch_bounds__(256) void qnade_prep_E(
    const float* __restrict__ W1, float* __restrict__ Et)
{
    int i = blockIdx.x * 256 + threadIdx.x;
    float w = W1[i] * C2L;
    Et[i]           = __builtin_amdgcn_exp2f(w);
    Et[DS * HD + i] = __builtin_amdgcn_exp2f(-w);
}

__global__ __launch_bounds__(256) void qnade_prep_S(
    const float* __restrict__ W2, const float* __restrict__ b2, float* __restrict__ C01)
{
    __shared__ float p0[4], p1[4];
    int tid = threadIdx.x;
    float s0 = 0.0f, s1 = 0.0f;
    for (int h = tid; h < HD; h += 256) {
        float2 w = ((const float2*)W2)[h];
        s0 += w.x; s1 += w.y;
    }
    #pragma unroll
    for (int m = 1; m < 64; m <<= 1) {
        s0 += __shfl_xor(s0, m, 64);
        s1 += __shfl_xor(s1, m, 64);
    }
    if ((tid & 63) == 0) { p0[tid >> 6] = s0; p1[tid >> 6] = s1; }
    __syncthreads();
    if (tid == 0) {
        C01[0] = p0[0] + p0[1] + p0[2] + p0[3] + b2[0];
        C01[1] = p1[0] + p1[1] + p1[2] + p1[3] + b2[1];
    }
}

// token-paste helpers (complete paste BEFORE member access)
#define TV(S, N) t##S##N
#define EV(S, N) e##S##N
#define FV(S, N) f##S##N

// Montgomery batch inversion + fused recovery/dot; one ds_write_b64 at end.
#define CHAIN(S, MIDX, SLOT) do {                                             \
    v2f q1 = pk_add(TV(S,0), one);                                            \
    v2f q2 = pk_fma(q1, TV(S,1), q1);                                         \
    v2f q3 = pk_fma(q2, TV(S,2), q2);                                         \
    v2f q4 = pk_fma(q3, TV(S,3), q3);                                         \
    v2f q5 = pk_fma(q4, TV(S,4), q4);                                         \
    v2f q6 = pk_fma(q5, TV(S,5), q5);                                         \
    v2f q7 = pk_fma(q6, TV(S,6), q6);                                         \
    v2f q8 = pk_fma(q7, TV(S,7), q7);                                         \
    float P = q8.x * q8.y;                                                    \
    float R = __builtin_amdgcn_rcpf(P);                                       \
    v2f RR = (v2f){R * q8.y, R * q8.x};                                       \
    v2f r7 = pk_mul(RR, q7);                                                  \
    v2f A0 = pk_mul(r7, w20[7]);                                              \
    v2f A1 = pk_mul(r7, w21[7]);                                              \
    RR = pk_fma(RR, TV(S,7), RR);                                             \
    v2f r6 = pk_mul(RR, q6); A0 = pk_fma(r6, w20[6], A0); A1 = pk_fma(r6, w21[6], A1); RR = pk_fma(RR, TV(S,6), RR); \
    v2f r5 = pk_mul(RR, q5); A0 = pk_fma(r5, w20[5], A0); A1 = pk_fma(r5, w21[5], A1); RR = pk_fma(RR, TV(S,5), RR); \
    v2f r4 = pk_mul(RR, q4); A0 = pk_fma(r4, w20[4], A0); A1 = pk_fma(r4, w21[4], A1); RR = pk_fma(RR, TV(S,4), RR); \
    v2f r3 = pk_mul(RR, q3); A0 = pk_fma(r3, w20[3], A0); A1 = pk_fma(r3, w21[3], A1); RR = pk_fma(RR, TV(S,3), RR); \
    v2f r2 = pk_mul(RR, q2); A0 = pk_fma(r2, w20[2], A0); A1 = pk_fma(r2, w21[2], A1); RR = pk_fma(RR, TV(S,2), RR); \
    v2f r1 = pk_mul(RR, q1); A0 = pk_fma(r1, w20[1], A0); A1 = pk_fma(r1, w21[1], A1); RR = pk_fma(RR, TV(S,1), RR); \
    A0 = pk_fma(RR, w20[0], A0); A1 = pk_fma(RR, w21[0], A1);                 \
    parts[MIDX][SLOT][tid] = make_float2(A0.x + A0.y, A1.x + A1.y);           \
} while (0)

#define TUPD_E(S) do {                                                        \
    TV(S,0) = pk_mul(TV(S,0), (v2f){EV(S,0).x, EV(S,0).y});                   \
    TV(S,1) = pk_mul(TV(S,1), (v2f){EV(S,0).z, EV(S,0).w});                   \
    TV(S,2) = pk_mul(TV(S,2), (v2f){EV(S,1).x, EV(S,1).y});                   \
    TV(S,3) = pk_mul(TV(S,3), (v2f){EV(S,1).z, EV(S,1).w});                   \
    TV(S,4) = pk_mul(TV(S,4), (v2f){EV(S,2).x, EV(S,2).y});                   \
    TV(S,5) = pk_mul(TV(S,5), (v2f){EV(S,2).z, EV(S,2).w});                   \
    TV(S,6) = pk_mul(TV(S,6), (v2f){EV(S,3).x, EV(S,3).y});                   \
    TV(S,7) = pk_mul(TV(S,7), (v2f){EV(S,3).z, EV(S,3).w});                   \
} while (0)

#define TUPD_F(S) do {                                                        \
    TV(S,0) = pk_mul(TV(S,0), (v2f){FV(S,0).x, FV(S,0).y});                   \
    TV(S,1) = pk_mul(TV(S,1), (v2f){FV(S,0).z, FV(S,0).w});                   \
    TV(S,2) = pk_mul(TV(S,2), (v2f){FV(S,1).x, FV(S,1).y});                   \
    TV(S,3) = pk_mul(TV(S,3), (v2f){FV(S,1).z, FV(S,1).w});                   \
    TV(S,4) = pk_mul(TV(S,4), (v2f){FV(S,2).x, FV(S,2).y});                   \
    TV(S,5) = pk_mul(TV(S,5), (v2f){FV(S,2).z, FV(S,2).w});                   \
    TV(S,6) = pk_mul(TV(S,6), (v2f){FV(S,3).x, FV(S,3).y});                   \
    TV(S,7) = pk_mul(TV(S,7), (v2f){FV(S,3).z, FV(S,3).w});                   \
} while (0)

#define LOAD_E(S) do {                                                        \
    unsigned off_ = (((msk##S >> nd) & 1ull) ? 0u : (unsigned)(DS * HD)) + nd * (unsigned)HD; \
    const float4* ep_ = (const float4*)(Et + off_) + tq;                      \
    EV(S,0) = ep_[0]; EV(S,1) = ep_[64]; EV(S,2) = ep_[128]; EV(S,3) = ep_[192]; \
} while (0)

#define LOAD_F(S) do {                                                        \
    unsigned off_ = (((msk##S >> nd) & 1ull) ? 0u : (unsigned)(DS * HD)) + nd * (unsigned)HD; \
    const float4* ep_ = (const float4*)(Et + off_) + tq;                      \
    FV(S,0) = ep_[0]; FV(S,1) = ep_[64]; FV(S,2) = ep_[128]; FV(S,3) = ep_[192]; \
} while (0)

// ---- main: one block = 2 samples; each wave owns a 1024-elem quarter.
// E registers double-buffered (ping-pong, unroll-2). CH=4 keeps LDS ~17 KB;
// launch_bounds (256,3) — the proven-safe VGPR cap (R12's (256,4) spilled).
__global__ __launch_bounds__(256, 3) void qnade_main(
    const float* __restrict__ x, const float* __restrict__ b1,
    const float* __restrict__ W2, const float* __restrict__ Et,
    const float* __restrict__ C01, float* __restrict__ out)
{
    __shared__ float2 parts[2][CH][256];   // 16 KB
    __shared__ float2 fin[2][DS];          // 1 KB

    const int tid  = threadIdx.x;
    const int lane = tid & 63;
    const int wv   = tid >> 6;
    const int n0   = blockIdx.x * 2;
    const int hbase = wv * 1024 + lane * 4;   // + q*256
    const int tq    = wv * 256 + lane;        // float4 index of hbase

    // W2 columns as (even,odd)-element pairs — shared by both samples
    v2f w20[8], w21[8];
    #pragma unroll
    for (int q = 0; q < 4; ++q) {
        const float4* p = (const float4*)(W2 + 2 * (hbase + q * 256));
        float4 A = p[0], B = p[1];
        w20[2*q]   = (v2f){A.x, A.z};  w21[2*q]   = (v2f){A.y, A.w};
        w20[2*q+1] = (v2f){B.x, B.z};  w21[2*q+1] = (v2f){B.y, B.w};
    }

    // t0 = e^{2*b1}, identical start for both samples
    v2f tA0, tA1, tA2, tA3, tA4, tA5, tA6, tA7;
    {
        float4 b0 = *(const float4*)(b1 + hbase);
        float4 b1q = *(const float4*)(b1 + hbase + 256);
        float4 b2q = *(const float4*)(b1 + hbase + 512);
        float4 b3q = *(const float4*)(b1 + hbase + 768);
        tA0 = (v2f){__builtin_amdgcn_exp2f(b0.x * C2L), __builtin_amdgcn_exp2f(b0.y * C2L)};
        tA1 = (v2f){__builtin_amdgcn_exp2f(b0.z * C2L), __builtin_amdgcn_exp2f(b0.w * C2L)};
        tA2 = (v2f){__builtin_amdgcn_exp2f(b1q.x * C2L), __builtin_amdgcn_exp2f(b1q.y * C2L)};
        tA3 = (v2f){__builtin_amdgcn_exp2f(b1q.z * C2L), __builtin_amdgcn_exp2f(b1q.w * C2L)};
        tA4 = (v2f){__builtin_amdgcn_exp2f(b2q.x * C2L), __builtin_amdgcn_exp2f(b2q.y * C2L)};
        tA5 = (v2f){__builtin_amdgcn_exp2f(b2q.z * C2L), __builtin_amdgcn_exp2f(b2q.w * C2L)};
        tA6 = (v2f){__builtin_amdgcn_exp2f(b3q.x * C2L), __builtin_amdgcn_exp2f(b3q.y * C2L)};
        tA7 = (v2f){__builtin_amdgcn_exp2f(b3q.z * C2L), __builtin_amdgcn_exp2f(b3q.w * C2L)};
    }
    v2f tB0=tA0, tB1=tA1, tB2=tA2, tB3=tA3, tB4=tA4, tB5=tA5, tB6=tA6, tB7=tA7;

    const unsigned long long mskA = __ballot(x[n0 * DS + lane] > 0.0f);
    const unsigned long long mskB = __ballot(x[(n0 + 1) * DS + lane] > 0.0f);
    const v2f one = (v2f){1.0f, 1.0f};

    float4 eA0, eA1, eA2, eA3, eB0, eB1, eB2, eB3;   // buffer E (even steps)
    float4 fA0, fA1, fA2, fA3, fB0, fB1, fB2, fB3;   // buffer F (odd steps)

    unsigned nd = 0;
    LOAD_E(A); LOAD_E(B);      // step 0
    nd = 1;
    LOAD_F(A); LOAD_F(B);      // step 1

    int d = 0;
    for (int cc = 0; cc < NCH; ++cc) {
        for (int s8 = 0; s8 < CH; s8 += 2) {
            // even step d: consume E, then reload E for d+2
            CHAIN(A, 0, s8);
            CHAIN(B, 1, s8);
            TUPD_E(A); TUPD_E(B);
            nd = (unsigned)(d + 2) & (DS - 1);
            LOAD_E(A); LOAD_E(B);
            ++d;
            // odd step d: consume F, then reload F for d+2
            CHAIN(A, 0, s8 + 1);
            CHAIN(B, 1, s8 + 1);
            TUPD_F(A); TUPD_F(B);
            nd = (unsigned)(d + 2) & (DS - 1);
            LOAD_F(A); LOAD_F(B);
            ++d;
        }

        __syncthreads();
        // chunk reduce: 8 (sample,step) units x 256 partials; 32 threads/unit
        {
            const int j  = tid & 31;
            const int u  = tid >> 5;          // 0..7
            const int m  = u & 1;
            const int sr = u >> 1;            // 0..3
            v2f s = (v2f){0.0f, 0.0f};
            #pragma unroll
            for (int i = 0; i < 8; ++i) {
                float2 v = parts[m][sr][j + 32 * i];
                s = pk_add(s, (v2f){v.x, v.y});
            }
            s = pk_add(s, swz_xor<0x041F>(s));   // xor 1
            s = pk_add(s, swz_xor<0x081F>(s));   // xor 2
            s = pk_add(s, swz_xor<0x101F>(s));   // xor 4
            s = pk_add(s, swz_xor<0x201F>(s));   // xor 8
            s = pk_add(s, swz_xor<0x401F>(s));   // xor 16
            if (j == 0) fin[m][cc * CH + sr] = make_float2(s.x, s.y);
        }
        __syncthreads();
    }

    // deferred epilogue: wave 0 -> sample A, wave 1 -> sample B; lane = step
    if (wv < 2) {
        const unsigned long long mm = wv ? mskB : mskA;
        float2 sv = fin[wv][lane];
        float dot0 = __builtin_fmaf(-2.0f, sv.x, C01[0]);
        float dot1 = __builtin_fmaf(-2.0f, sv.y, C01[1]);
        float o0 = fast_tanh(dot0);
        float o1 = fast_tanh(dot1);
        float nrm = sqrtf(__builtin_fmaf(o0, o0, o1 * o1));
        nrm = fmaxf(nrm, 1e-12f);
        float sel = ((mm >> lane) & 1ull) ? o0 : o1;
        float v = sel * __builtin_amdgcn_rcpf(nrm);
        v *= __shfl_xor(v, 1, 64);
        v *= __shfl_xor(v, 2, 64);
        v *= __shfl_xor(v, 4, 64);
        v *= __shfl_xor(v, 8, 64);
        v *= __shfl_xor(v, 16, 64);
        v *= __shfl_xor(v, 32, 64);
        if (lane == 0) out[n0 + wv] = v;
    }
}

// ---- fallback if ws too small ----
__global__ __launch_bounds__(256) void qnade_fallback(
    const float* __restrict__ x, const float* __restrict__ W1,
    const float* __restrict__ b1, const float* __restrict__ W2,
    const float* __restrict__ b2, float* __restrict__ out)
{
    __shared__ __align__(16) float w20s[HD];
    __shared__ __align__(16) float w21s[HD];
    const int tid = threadIdx.x;
    for (int i = tid; i < HD; i += 256) {
        float2 w = ((const float2*)W2)[i];
        w20s[i] = w.x;
        w21s[i] = w.y;
    }
    const int lane = tid & 63;
    const int wv   = tid >> 6;
    const int n    = (blockIdx.x << 2) + wv;
    const float b20 = b2[0];
    const float b21 = b2[1];
    const float xv = x[n * DS + lane];
    float4 a[16];
    const float4* b1v = (const float4*)b1;
    #pragma unroll
    for (int q = 0; q < 16; ++q) a[q] = b1v[q * 64 + lane];
    __syncthreads();
    const float4* w20v = (const float4*)w20s;
    const float4* w21v = (const float4*)w21s;
    float wav = 1.0f;
    for (int d = 0; d < DS; ++d) {
        const float xd = __shfl(xv, d, 64);
        const float4* w1v = (const float4*)(W1 + d * HD);
        float dot0 = 0.0f, dot1 = 0.0f;
        #pragma unroll
        for (int q = 0; q < 16; ++q) {
            float4 w1 = w1v[q * 64 + lane];
            float4 av = a[q];
            float h0 = fast_tanh(av.x);
            float h1 = fast_tanh(av.y);
            float h2 = fast_tanh(av.z);
            float h3 = fast_tanh(av.w);
            float4 c0 = w20v[q * 64 + lane];
            float4 c1 = w21v[q * 64 + lane];
            dot0 = fmaf(h0, c0.x, dot0); dot0 = fmaf(h1, c0.y, dot0);
            dot0 = fmaf(h2, c0.z, dot0); dot0 = fmaf(h3, c0.w, dot0);
            dot1 = fmaf(h0, c1.x, dot1); dot1 = fmaf(h1, c1.y, dot1);
            dot1 = fmaf(h2, c1.z, dot1); dot1 = fmaf(h3, c1.w, dot1);
            av.x = fmaf(xd, w1.x, av.x); av.y = fmaf(xd, w1.y, av.y);
            av.z = fmaf(xd, w1.z, av.z); av.w = fmaf(xd, w1.w, av.w);
            a[q] = av;
        }
        #pragma unroll
        for (int m = 1; m < 64; m <<= 1) {
            dot0 += __shfl_xor(dot0, m, 64);
            dot1 += __shfl_xor(dot1, m, 64);
        }
        float o0 = fast_tanh(dot0 + b20);
        float o1 = fast_tanh(dot1 + b21);
        float nrm = sqrtf(fmaf(o0, o0, o1 * o1));
        nrm = fmaxf(nrm, 1e-12f);
        float sel = (xd > 0.0f) ? o0 : o1;
        wav *= sel / nrm;
    }
    out[n] = wav;
}

extern "C" void kernel_launch(void* const* d_in, const int* in_sizes, int n_in,
                              void* d_out, int out_size, void* d_ws, size_t ws_size,
                              hipStream_t stream) {
    const float* x  = (const float*)d_in[0];
    const float* W1 = (const float*)d_in[1];
    const float* b1 = (const float*)d_in[2];
    const float* W2 = (const float*)d_in[3];
    const float* b2 = (const float*)d_in[4];
    float* out = (float*)d_out;

    const size_t need = (size_t)(2 * DS * HD + 2) * sizeof(float);
    if (ws_size >= need) {
        float* Et  = (float*)d_ws;           // [2][DS][HD]
        float* C01 = Et + 2 * DS * HD;
        hipLaunchKernelGGL(qnade_prep_E, dim3(DS * HD / 256), dim3(256), 0, stream, W1, Et);
        hipLaunchKernelGGL(qnade_prep_S, dim3(1), dim3(256), 0, stream, W2, b2, C01);
        hipLaunchKernelGGL(qnade_main, dim3(NS / 2), dim3(256), 0, stream, x, b1, W2, Et, C01, out);
    } else {
        hipLaunchKernelGGL(qnade_fallback, dim3(NS / 4), dim3(256), 0, stream, x, W1, b1, W2, b2, out);
    }
}

// Round 15
// 405.164 us; speedup vs baseline: 4.7839x; 1.0188x over previous
//
#include <hip/hip_runtime.h>
#include <math.h>

#define NS 8192
#define DS 64
#define HD 4096
#define C2L 2.8853900817779268f   // 2*log2(e)
#define CH 8                      // steps per chunk (R11 winner)
#define NCH (DS / CH)

typedef float v2f __attribute__((ext_vector_type(2)));

__device__ __forceinline__ v2f pk_add(v2f a, v2f b) {
    v2f d; asm("v_pk_add_f32 %0, %1, %2" : "=v"(d) : "v"(a), "v"(b)); return d;
}
__device__ __forceinline__ v2f pk_mul(v2f a, v2f b) {
    v2f d; asm("v_pk_mul_f32 %0, %1, %2" : "=v"(d) : "v"(a), "v"(b)); return d;
}
__device__ __forceinline__ v2f pk_fma(v2f a, v2f b, v2f c) {
    v2f d; asm("v_pk_fma_f32 %0, %1, %2, %3" : "=v"(d) : "v"(a), "v"(b), "v"(c)); return d;
}

__device__ __forceinline__ float fast_tanh(float x) {
    float t = __builtin_amdgcn_exp2f(x * C2L);
    float r = __builtin_amdgcn_rcpf(t + 1.0f);
    return __builtin_fmaf(-2.0f, r, 1.0f);
}

template <int PATT>
__device__ __forceinline__ v2f swz_xor(v2f v) {
    v2f d;
    d.x = __int_as_float(__builtin_amdgcn_ds_swizzle(__float_as_int(v.x), PATT));
    d.y = __int_as_float(__builtin_amdgcn_ds_swizzle(__float_as_int(v.y), PATT));
    return d;
}

// ---- setup: Et[0][d][h]=e^{+2W1}, Et[1][d][h]=e^{-2W1}; C01 = colsum(W2)+b2 ----
__global__ __launch_bounds__(256) void qnade_prep_E(
    const float* __restrict__ W1, float* __restrict__ Et)
{
    int i = blockIdx.x * 256 + threadIdx.x;
    float w = W1[i] * C2L;
    Et[i]           = __builtin_amdgcn_exp2f(w);
    Et[DS * HD + i] = __builtin_amdgcn_exp2f(-w);
}

__global__ __launch_bounds__(256) void qnade_prep_S(
    const float* __restrict__ W2, const float* __restrict__ b2, float* __restrict__ C01)
{
    __shared__ float p0[4], p1[4];
    int tid = threadIdx.x;
    float s0 = 0.0f, s1 = 0.0f;
    for (int h = tid; h < HD; h += 256) {
        float2 w = ((const float2*)W2)[h];
        s0 += w.x; s1 += w.y;
    }
    #pragma unroll
    for (int m = 1; m < 64; m <<= 1) {
        s0 += __shfl_xor(s0, m, 64);
        s1 += __shfl_xor(s1, m, 64);
    }
    if ((tid & 63) == 0) { p0[tid >> 6] = s0; p1[tid >> 6] = s1; }
    __syncthreads();
    if (tid == 0) {
        C01[0] = p0[0] + p0[1] + p0[2] + p0[3] + b2[0];
        C01[1] = p1[0] + p1[1] + p1[2] + p1[3] + b2[1];
    }
}

// token-paste helpers (complete paste BEFORE member access)
#define TV(S, N) t##S##N
#define EV(S, N) e##S##N
#define FV(S, N) f##S##N

// Montgomery batch inversion + fused recovery/dot; one ds_write_b64 at end.
#define CHAIN(S, MIDX, SLOT) do {                                             \
    v2f q1 = pk_add(TV(S,0), one);                                            \
    v2f q2 = pk_fma(q1, TV(S,1), q1);                                         \
    v2f q3 = pk_fma(q2, TV(S,2), q2);                                         \
    v2f q4 = pk_fma(q3, TV(S,3), q3);                                         \
    v2f q5 = pk_fma(q4, TV(S,4), q4);                                         \
    v2f q6 = pk_fma(q5, TV(S,5), q5);                                         \
    v2f q7 = pk_fma(q6, TV(S,6), q6);                                         \
    v2f q8 = pk_fma(q7, TV(S,7), q7);                                         \
    float P = q8.x * q8.y;                                                    \
    float R = __builtin_amdgcn_rcpf(P);                                       \
    v2f RR = (v2f){R * q8.y, R * q8.x};                                       \
    v2f r7 = pk_mul(RR, q7);                                                  \
    v2f A0 = pk_mul(r7, w20[7]);                                              \
    v2f A1 = pk_mul(r7, w21[7]);                                              \
    RR = pk_fma(RR, TV(S,7), RR);                                             \
    v2f r6 = pk_mul(RR, q6); A0 = pk_fma(r6, w20[6], A0); A1 = pk_fma(r6, w21[6], A1); RR = pk_fma(RR, TV(S,6), RR); \
    v2f r5 = pk_mul(RR, q5); A0 = pk_fma(r5, w20[5], A0); A1 = pk_fma(r5, w21[5], A1); RR = pk_fma(RR, TV(S,5), RR); \
    v2f r4 = pk_mul(RR, q4); A0 = pk_fma(r4, w20[4], A0); A1 = pk_fma(r4, w21[4], A1); RR = pk_fma(RR, TV(S,4), RR); \
    v2f r3 = pk_mul(RR, q3); A0 = pk_fma(r3, w20[3], A0); A1 = pk_fma(r3, w21[3], A1); RR = pk_fma(RR, TV(S,3), RR); \
    v2f r2 = pk_mul(RR, q2); A0 = pk_fma(r2, w20[2], A0); A1 = pk_fma(r2, w21[2], A1); RR = pk_fma(RR, TV(S,2), RR); \
    v2f r1 = pk_mul(RR, q1); A0 = pk_fma(r1, w20[1], A0); A1 = pk_fma(r1, w21[1], A1); RR = pk_fma(RR, TV(S,1), RR); \
    A0 = pk_fma(RR, w20[0], A0); A1 = pk_fma(RR, w21[0], A1);                 \
    parts[MIDX][SLOT][tid] = make_float2(A0.x + A0.y, A1.x + A1.y);           \
} while (0)

#define TUPD_E(S) do {                                                        \
    TV(S,0) = pk_mul(TV(S,0), (v2f){EV(S,0).x, EV(S,0).y});                   \
    TV(S,1) = pk_mul(TV(S,1), (v2f){EV(S,0).z, EV(S,0).w});                   \
    TV(S,2) = pk_mul(TV(S,2), (v2f){EV(S,1).x, EV(S,1).y});                   \
    TV(S,3) = pk_mul(TV(S,3), (v2f){EV(S,1).z, EV(S,1).w});                   \
    TV(S,4) = pk_mul(TV(S,4), (v2f){EV(S,2).x, EV(S,2).y});                   \
    TV(S,5) = pk_mul(TV(S,5), (v2f){EV(S,2).z, EV(S,2).w});                   \
    TV(S,6) = pk_mul(TV(S,6), (v2f){EV(S,3).x, EV(S,3).y});                   \
    TV(S,7) = pk_mul(TV(S,7), (v2f){EV(S,3).z, EV(S,3).w});                   \
} while (0)

#define TUPD_F(S) do {                                                        \
    TV(S,0) = pk_mul(TV(S,0), (v2f){FV(S,0).x, FV(S,0).y});                   \
    TV(S,1) = pk_mul(TV(S,1), (v2f){FV(S,0).z, FV(S,0).w});                   \
    TV(S,2) = pk_mul(TV(S,2), (v2f){FV(S,1).x, FV(S,1).y});                   \
    TV(S,3) = pk_mul(TV(S,3), (v2f){FV(S,1).z, FV(S,1).w});                   \
    TV(S,4) = pk_mul(TV(S,4), (v2f){FV(S,2).x, FV(S,2).y});                   \
    TV(S,5) = pk_mul(TV(S,5), (v2f){FV(S,2).z, FV(S,2).w});                   \
    TV(S,6) = pk_mul(TV(S,6), (v2f){FV(S,3).x, FV(S,3).y});                   \
    TV(S,7) = pk_mul(TV(S,7), (v2f){FV(S,3).z, FV(S,3).w});                   \
} while (0)

#define LOAD_E(S) do {                                                        \
    unsigned off_ = (((msk##S >> nd) & 1ull) ? 0u : (unsigned)(DS * HD)) + nd * (unsigned)HD; \
    const float4* ep_ = (const float4*)(Et + off_) + tq;                      \
    EV(S,0) = ep_[0]; EV(S,1) = ep_[64]; EV(S,2) = ep_[128]; EV(S,3) = ep_[192]; \
} while (0)

#define LOAD_F(S) do {                                                        \
    unsigned off_ = (((msk##S >> nd) & 1ull) ? 0u : (unsigned)(DS * HD)) + nd * (unsigned)HD; \
    const float4* ep_ = (const float4*)(Et + off_) + tq;                      \
    FV(S,0) = ep_[0]; FV(S,1) = ep_[64]; FV(S,2) = ep_[128]; FV(S,3) = ep_[192]; \
} while (0)

// ---- main: one block = 2 samples; each wave owns a 1024-elem quarter.
// E registers double-buffered (ping-pong, unroll-2). sched_barrier(0) after
// each LOAD group prevents the scheduler from sinking the prefetch loads to
// their consume point (R11/R13's VGPR=84 showed the distance had collapsed).
__global__ __launch_bounds__(256, 3) void qnade_main(
    const float* __restrict__ x, const float* __restrict__ b1,
    const float* __restrict__ W2, const float* __restrict__ Et,
    const float* __restrict__ C01, float* __restrict__ out)
{
    __shared__ float2 parts[2][CH][256];   // 32 KB
    __shared__ float2 fin[2][DS];          // 1 KB

    const int tid  = threadIdx.x;
    const int lane = tid & 63;
    const int wv   = tid >> 6;
    const int n0   = blockIdx.x * 2;
    const int hbase = wv * 1024 + lane * 4;   // + q*256
    const int tq    = wv * 256 + lane;        // float4 index of hbase

    // W2 columns as (even,odd)-element pairs — shared by both samples
    v2f w20[8], w21[8];
    #pragma unroll
    for (int q = 0; q < 4; ++q) {
        const float4* p = (const float4*)(W2 + 2 * (hbase + q * 256));
        float4 A = p[0], B = p[1];
        w20[2*q]   = (v2f){A.x, A.z};  w21[2*q]   = (v2f){A.y, A.w};
        w20[2*q+1] = (v2f){B.x, B.z};  w21[2*q+1] = (v2f){B.y, B.w};
    }

    // t0 = e^{2*b1}, identical start for both samples
    v2f tA0, tA1, tA2, tA3, tA4, tA5, tA6, tA7;
    {
        float4 b0 = *(const float4*)(b1 + hbase);
        float4 b1q = *(const float4*)(b1 + hbase + 256);
        float4 b2q = *(const float4*)(b1 + hbase + 512);
        float4 b3q = *(const float4*)(b1 + hbase + 768);
        tA0 = (v2f){__builtin_amdgcn_exp2f(b0.x * C2L), __builtin_amdgcn_exp2f(b0.y * C2L)};
        tA1 = (v2f){__builtin_amdgcn_exp2f(b0.z * C2L), __builtin_amdgcn_exp2f(b0.w * C2L)};
        tA2 = (v2f){__builtin_amdgcn_exp2f(b1q.x * C2L), __builtin_amdgcn_exp2f(b1q.y * C2L)};
        tA3 = (v2f){__builtin_amdgcn_exp2f(b1q.z * C2L), __builtin_amdgcn_exp2f(b1q.w * C2L)};
        tA4 = (v2f){__builtin_amdgcn_exp2f(b2q.x * C2L), __builtin_amdgcn_exp2f(b2q.y * C2L)};
        tA5 = (v2f){__builtin_amdgcn_exp2f(b2q.z * C2L), __builtin_amdgcn_exp2f(b2q.w * C2L)};
        tA6 = (v2f){__builtin_amdgcn_exp2f(b3q.x * C2L), __builtin_amdgcn_exp2f(b3q.y * C2L)};
        tA7 = (v2f){__builtin_amdgcn_exp2f(b3q.z * C2L), __builtin_amdgcn_exp2f(b3q.w * C2L)};
    }
    v2f tB0=tA0, tB1=tA1, tB2=tA2, tB3=tA3, tB4=tA4, tB5=tA5, tB6=tA6, tB7=tA7;

    const unsigned long long mskA = __ballot(x[n0 * DS + lane] > 0.0f);
    const unsigned long long mskB = __ballot(x[(n0 + 1) * DS + lane] > 0.0f);
    const v2f one = (v2f){1.0f, 1.0f};

    float4 eA0, eA1, eA2, eA3, eB0, eB1, eB2, eB3;   // buffer E (even steps)
    float4 fA0, fA1, fA2, fA3, fB0, fB1, fB2, fB3;   // buffer F (odd steps)

    unsigned nd = 0;
    LOAD_E(A); LOAD_E(B);      // step 0
    nd = 1;
    LOAD_F(A); LOAD_F(B);      // step 1
    __builtin_amdgcn_sched_barrier(0);

    int d = 0;
    for (int cc = 0; cc < NCH; ++cc) {
        for (int s8 = 0; s8 < CH; s8 += 2) {
            // even step d: consume E, then reload E for d+2
            CHAIN(A, 0, s8);
            CHAIN(B, 1, s8);
            TUPD_E(A); TUPD_E(B);
            nd = (unsigned)(d + 2) & (DS - 1);
            LOAD_E(A); LOAD_E(B);
            __builtin_amdgcn_sched_barrier(0);   // keep E-loads ahead of odd CHAIN
            ++d;
            // odd step d: consume F, then reload F for d+2
            CHAIN(A, 0, s8 + 1);
            CHAIN(B, 1, s8 + 1);
            TUPD_F(A); TUPD_F(B);
            nd = (unsigned)(d + 2) & (DS - 1);
            LOAD_F(A); LOAD_F(B);
            __builtin_amdgcn_sched_barrier(0);   // keep F-loads ahead of next even CHAIN
            ++d;
        }

        __syncthreads();
        // chunk reduce: 16 (sample,step) units x 256 partials; 16 threads/unit
        {
            const int j  = tid & 15;
            const int u  = tid >> 4;
            const int m  = u & 1;
            const int sr = u >> 1;
            v2f s = (v2f){0.0f, 0.0f};
            #pragma unroll
            for (int i = 0; i < 16; ++i) {
                float2 v = parts[m][sr][j + 16 * i];
                s = pk_add(s, (v2f){v.x, v.y});
            }
            s = pk_add(s, swz_xor<0x041F>(s));   // xor 1
            s = pk_add(s, swz_xor<0x081F>(s));   // xor 2
            s = pk_add(s, swz_xor<0x101F>(s));   // xor 4
            s = pk_add(s, swz_xor<0x201F>(s));   // xor 8
            if (j == 0) fin[m][cc * CH + sr] = make_float2(s.x, s.y);
        }
        __syncthreads();
    }

    // deferred epilogue: wave 0 -> sample A, wave 1 -> sample B; lane = step
    if (wv < 2) {
        const unsigned long long mm = wv ? mskB : mskA;
        float2 sv = fin[wv][lane];
        float dot0 = __builtin_fmaf(-2.0f, sv.x, C01[0]);
        float dot1 = __builtin_fmaf(-2.0f, sv.y, C01[1]);
        float o0 = fast_tanh(dot0);
        float o1 = fast_tanh(dot1);
        float nrm = sqrtf(__builtin_fmaf(o0, o0, o1 * o1));
        nrm = fmaxf(nrm, 1e-12f);
        float sel = ((mm >> lane) & 1ull) ? o0 : o1;
        float v = sel * __builtin_amdgcn_rcpf(nrm);
        v *= __shfl_xor(v, 1, 64);
        v *= __shfl_xor(v, 2, 64);
        v *= __shfl_xor(v, 4, 64);
        v *= __shfl_xor(v, 8, 64);
        v *= __shfl_xor(v, 16, 64);
        v *= __shfl_xor(v, 32, 64);
        if (lane == 0) out[n0 + wv] = v;
    }
}

// ---- fallback if ws too small ----
__global__ __launch_bounds__(256) void qnade_fallback(
    const float* __restrict__ x, const float* __restrict__ W1,
    const float* __restrict__ b1, const float* __restrict__ W2,
    const float* __restrict__ b2, float* __restrict__ out)
{
    __shared__ __align__(16) float w20s[HD];
    __shared__ __align__(16) float w21s[HD];
    const int tid = threadIdx.x;
    for (int i = tid; i < HD; i += 256) {
        float2 w = ((const float2*)W2)[i];
        w20s[i] = w.x;
        w21s[i] = w.y;
    }
    const int lane = tid & 63;
    const int wv   = tid >> 6;
    const int n    = (blockIdx.x << 2) + wv;
    const float b20 = b2[0];
    const float b21 = b2[1];
    const float xv = x[n * DS + lane];
    float4 a[16];
    const float4* b1v = (const float4*)b1;
    #pragma unroll
    for (int q = 0; q < 16; ++q) a[q] = b1v[q * 64 + lane];
    __syncthreads();
    const float4* w20v = (const float4*)w20s;
    const float4* w21v = (const float4*)w21s;
    float wav = 1.0f;
    for (int d = 0; d < DS; ++d) {
        const float xd = __shfl(xv, d, 64);
        const float4* w1v = (const float4*)(W1 + d * HD);
        float dot0 = 0.0f, dot1 = 0.0f;
        #pragma unroll
        for (int q = 0; q < 16; ++q) {
            float4 w1 = w1v[q * 64 + lane];
            float4 av = a[q];
            float h0 = fast_tanh(av.x);
            float h1 = fast_tanh(av.y);
            float h2 = fast_tanh(av.z);
            float h3 = fast_tanh(av.w);
            float4 c0 = w20v[q * 64 + lane];
            float4 c1 = w21v[q * 64 + lane];
            dot0 = fmaf(h0, c0.x, dot0); dot0 = fmaf(h1, c0.y, dot0);
            dot0 = fmaf(h2, c0.z, dot0); dot0 = fmaf(h3, c0.w, dot0);
            dot1 = fmaf(h0, c1.x, dot1); dot1 = fmaf(h1, c1.y, dot1);
            dot1 = fmaf(h2, c1.z, dot1); dot1 = fmaf(h3, c1.w, dot1);
            av.x = fmaf(xd, w1.x, av.x); av.y = fmaf(xd, w1.y, av.y);
            av.z = fmaf(xd, w1.z, av.z); av.w = fmaf(xd, w1.w, av.w);
            a[q] = av;
        }
        #pragma unroll
        for (int m = 1; m < 64; m <<= 1) {
            dot0 += __shfl_xor(dot0, m, 64);
            dot1 += __shfl_xor(dot1, m, 64);
        }
        float o0 = fast_tanh(dot0 + b20);
        float o1 = fast_tanh(dot1 + b21);
        float nrm = sqrtf(fmaf(o0, o0, o1 * o1));
        nrm = fmaxf(nrm, 1e-12f);
        float sel = (xd > 0.0f) ? o0 : o1;
        wav *= sel / nrm;
    }
    out[n] = wav;
}

extern "C" void kernel_launch(void* const* d_in, const int* in_sizes, int n_in,
                              void* d_out, int out_size, void* d_ws, size_t ws_size,
                              hipStream_t stream) {
    const float* x  = (const float*)d_in[0];
    const float* W1 = (const float*)d_in[1];
    const float* b1 = (const float*)d_in[2];
    const float* W2 = (const float*)d_in[3];
    const float* b2 = (const float*)d_in[4];
    float* out = (float*)d_out;

    const size_t need = (size_t)(2 * DS * HD + 2) * sizeof(float);
    if (ws_size >= need) {
        float* Et  = (float*)d_ws;           // [2][DS][HD]
        float* C01 = Et + 2 * DS * HD;
        hipLaunchKernelGGL(qnade_prep_E, dim3(DS * HD / 256), dim3(256), 0, stream, W1, Et);
        hipLaunchKernelGGL(qnade_prep_S, dim3(1), dim3(256), 0, stream, W2, b2, C01);
        hipLaunchKernelGGL(qnade_main, dim3(NS / 2), dim3(256), 0, stream, x, b1, W2, Et, C01, out);
    } else {
        hipLaunchKernelGGL(qnade_fallback, dim3(NS / 4), dim3(256), 0, stream, x, W1, b1, W2, b2, out);
    }
}